// Round 11
// baseline (343.769 us; speedup 1.0000x reference)
//
#include <hip/hip_runtime.h>
#include <stdint.h>

typedef unsigned short u16;
typedef unsigned int   u32;
typedef unsigned long long u64;

#define F_DIM 256
#define O_DIM 24
#define MARGIN  3.0f      // capture margin (>= 2E bf16-vs-fp32 score bound; validated R2-R9)
#define FMARGIN 3.0f      // rescore global filter margin (same bound)
#define WCAP 3072         // candidate slots per capture-wave (8 B each)
#define NWAVE_CAP 2048    // 4 mb * 64 chunks * 8 waves
#define CBUF 256          // LDS candidate slots per wave

#define AS1 __attribute__((address_space(1)))
#define AS3 __attribute__((address_space(3)))

typedef __bf16 bf16x8 __attribute__((ext_vector_type(8)));
typedef float  f32x4  __attribute__((ext_vector_type(4)));

__device__ __forceinline__ u32 ordf(float s) {
    u32 b = __float_as_uint(s);
    return (b & 0x80000000u) ? ~b : (b | 0x80000000u);
}
__device__ __forceinline__ u16 f2bf(float f) {   // round-to-nearest-even
    u32 u = __float_as_uint(f);
    u32 r = (u + 0x7FFFu + ((u >> 16) & 1u)) >> 16;
    return (u16)r;
}

// ---------------- init ----------------
__global__ void init_kernel(u64* best, int B) {
    int i = blockIdx.x * blockDim.x + threadIdx.x;
    if (i < B) best[i] = ~0ull;
}

// ---------------- t2 (fallback path only) ----------------
__global__ void t2_kernel(const float* __restrict__ X, float* __restrict__ t2,
                          int N, int Npad) {
    int tid = threadIdx.x;
    int row = blockIdx.x * 4 + (tid >> 6);
    int lane = tid & 63;
    if (row >= Npad) return;
    if (row >= N) { if (lane == 0) t2[row] = 1e30f; return; }
    float4 v = ((const float4*)(X + (size_t)row * F_DIM))[lane];
    float s = v.x * v.x + v.y * v.y + v.z * v.z + v.w * v.w;
    #pragma unroll
    for (int off = 32; off > 0; off >>= 1) s += __shfl_down(s, off, 64);
    if (lane == 0) t2[row] = s;
}

// ---------------- coalesced converter: fp32 row-major -> bf16 fragment order ----------------
__global__ __launch_bounds__(256) void convert_tile(const float* __restrict__ src,
        u16* __restrict__ dst, float* __restrict__ t2out, int nrows, int do_t2) {
    __shared__ u16 tl[8192];   // 16 KB
    const int tid = threadIdx.x;
    const int t = blockIdx.x, p = blockIdx.y;
    const int w = tid >> 6, L = tid & 63;
    const int col = L * 4;
    const int ks = col >> 5, j = col & 7, lhi = ((col >> 3) & 3) << 4;
    #pragma unroll
    for (int i = 0; i < 8; ++i) {
        int rloc = i * 4 + w;
        int grow = t * 128 + p * 32 + rloc;
        float4 v = make_float4(0.f, 0.f, 0.f, 0.f);
        if (grow < nrows) v = *(const float4*)(src + (size_t)grow * F_DIM + col);
        if (do_t2) {
            float s = v.x * v.x + v.y * v.y + v.z * v.z + v.w * v.w;
            #pragma unroll
            for (int off = 32; off > 0; off >>= 1) s += __shfl_down(s, off, 64);
            if (L == 0) t2out[grow] = (grow < nrows) ? s : 1e30f;
        }
        u16* q = &tl[ks * 1024 + (rloc >> 4) * 512 + (((rloc & 15) | lhi)) * 8 + j];
        q[0] = f2bf(v.x); q[1] = f2bf(v.y); q[2] = f2bf(v.z); q[3] = f2bf(v.w);
    }
    __syncthreads();
    const uint4* s4 = (const uint4*)tl;
    uint4* d4 = (uint4*)(dst + (size_t)t * 32768);
    #pragma unroll
    for (int v = 0; v < 4; ++v) {
        int lin = v * 256 + tid;
        int ksc = lin >> 7, subl = (lin >> 6) & 1, lane = lin & 63;
        d4[(ksc * 8 + 2 * p + subl) * 64 + lane] = s4[lin];
    }
}

// ---------------- main: M=512 LDS-shared bf16 MFMA + LDS-buffered candidate capture ----------------
__global__ __launch_bounds__(512, 1) void knn_mfma(
    const u16* __restrict__ xbf, const u16* __restrict__ xtbf,
    const float* __restrict__ t2, float* __restrict__ chunkmin,
    u32* __restrict__ wavecnt, u64* __restrict__ cands,
    int ntiles /*64-col tiles*/, int nch)
{
    __shared__ u16 sB[2][16384];   // 64 KB: B double buffer
    __shared__ u64 cbuf[8][CBUF];  // 16 KB: per-wave candidate buffers

    const int tid = threadIdx.x;
    const int L = tid & 63, w = tid >> 6;     // 8 waves
    const int id = blockIdx.x;
    const int slot = id & 7, rest = id >> 3;
    const int mb = rest & 3;                  // 512-row m-block
    const int chunk = slot + 8 * (rest >> 2); // 0..63
    const int gwave = ((mb << 6) | chunk) * 8 + w;
    const int t0 = (int)(((long long)chunk * ntiles) / nch);
    const int t1 = (int)(((long long)(chunk + 1) * ntiles) / nch);

    #define TBASE(nt) (xtbf + ((size_t)((nt) >> 1)) * 32768 + (size_t)((nt) & 1) * 2048)

    // ---- stage first B tile (async, 4 rounds x 512 threads x 16 B = 32 KB) ----
    {
        const u16* tb = TBASE(t0);
        const int ksq_half = tid >> 8;
        const int inner = tid & 255;
        #pragma unroll
        for (int r = 0; r < 4; ++r) {
            int ksq = r * 2 + ksq_half;
            __builtin_amdgcn_global_load_lds(
                (const AS1 u32*)(tb + ksq * 4096 + inner * 8),
                (AS3 u32*)&sB[0][0] + ksq * 1024 + inner * 4, 16, 0, 0);
        }
    }

    // ---- A fragments in registers: wave w owns rows mb*512 + w*64 .. +63 ----
    bf16x8 areg[32];
    {
        const int t128 = mb * 4 + (w >> 1);
        const u16* base = xbf + (size_t)t128 * 32768 + (size_t)((w & 1) * 4) * 512 + (size_t)L * 8;
        #pragma unroll
        for (int ks = 0; ks < 8; ++ks)
            #pragma unroll
            for (int i = 0; i < 4; ++i)
                areg[ks * 4 + i] = *(const bf16x8*)(base + ks * 4096 + i * 512);
    }

    float rowmin_reg[4][4];
    #pragma unroll
    for (int i = 0; i < 4; ++i)
        #pragma unroll
        for (int r = 0; r < 4; ++r) rowmin_reg[i][r] = 1e30f;

    u32 cnt_lds = 0;    // records in LDS buffer (wave-uniform)
    u32 gcur = 0;       // records flushed to global (wave-uniform)
    u64* const wreg = cands + (size_t)gwave * WCAP;

    __syncthreads();   // first B tile staged

    for (int nt = t0; nt < t1; ++nt) {
        const int cur = (nt - t0) & 1;
        if (nt + 1 < t1) {   // stage next tile into other buffer (drains at end barrier)
            const u16* tb = TBASE(nt + 1);
            const int ksq_half = tid >> 8;
            const int inner = tid & 255;
            #pragma unroll
            for (int r = 0; r < 4; ++r) {
                int ksq = r * 2 + ksq_half;
                __builtin_amdgcn_global_load_lds(
                    (const AS1 u32*)(tb + ksq * 4096 + inner * 8),
                    (AS3 u32*)&sB[cur ^ 1][0] + ksq * 1024 + inner * 4, 16, 0, 0);
            }
        }

        float t2v[4];
        #pragma unroll
        for (int c = 0; c < 4; ++c) t2v[c] = t2[nt * 64 + (L & 15) + c * 16];

        f32x4 acc[4][4];
        #pragma unroll
        for (int i = 0; i < 4; ++i)
            #pragma unroll
            for (int c = 0; c < 4; ++c)
                #pragma unroll
                for (int r = 0; r < 4; ++r) acc[i][c][r] = 0.f;

        #pragma unroll
        for (int ks = 0; ks < 8; ++ks) {
            bf16x8 bc[4];
            #pragma unroll
            for (int c = 0; c < 4; ++c)
                bc[c] = *(const bf16x8*)&sB[cur][ks * 2048 + c * 512 + L * 8];
            #pragma unroll
            for (int i = 0; i < 4; ++i)
                #pragma unroll
                for (int c = 0; c < 4; ++c)
                    acc[i][c] = __builtin_amdgcn_mfma_f32_16x16x32_bf16(areg[ks * 4 + i], bc[c], acc[i][c], 0, 0, 0);
        }

        // ---- epilogue ----
        const int colb = nt * 64 + (L & 15);
        float r4[4][4];
        #pragma unroll
        for (int i = 0; i < 4; ++i) {
            #pragma unroll
            for (int r = 0; r < 4; ++r) r4[i][r] = 1e30f;
            #pragma unroll
            for (int c = 0; c < 4; ++c)
                #pragma unroll
                for (int r = 0; r < 4; ++r)
                    r4[i][r] = fminf(r4[i][r], fmaf(-2.f, acc[i][c][r], t2v[c]));
        }

        // threshold base (subset-min of row's bf16 scores: safe with MARGIN >= 2E)
        float thb[4][4];
        if (nt == t0) {
            #pragma unroll
            for (int i = 0; i < 4; ++i)
                #pragma unroll
                for (int r = 0; r < 4; ++r) rowmin_reg[i][r] = r4[i][r];
            #pragma unroll
            for (int st = 1; st <= 8; st <<= 1)
                #pragma unroll
                for (int i = 0; i < 4; ++i)
                    #pragma unroll
                    for (int r = 0; r < 4; ++r)
                        rowmin_reg[i][r] = fminf(rowmin_reg[i][r], __shfl_xor(rowmin_reg[i][r], st, 64));
            #pragma unroll
            for (int i = 0; i < 4; ++i)
                #pragma unroll
                for (int r = 0; r < 4; ++r) thb[i][r] = rowmin_reg[i][r];
        } else {
            #pragma unroll
            for (int i = 0; i < 4; ++i)
                #pragma unroll
                for (int r = 0; r < 4; ++r) thb[i][r] = fminf(rowmin_reg[i][r], r4[i][r]);
        }

        bool anyhit = false;
        #pragma unroll
        for (int i = 0; i < 4; ++i)
            #pragma unroll
            for (int r = 0; r < 4; ++r)
                anyhit = anyhit || (r4[i][r] < thb[i][r] + MARGIN);

        if (__any(anyhit)) {
            u32 cnt = 0;
            #pragma unroll
            for (int i = 0; i < 4; ++i)
                #pragma unroll
                for (int r = 0; r < 4; ++r) {
                    float th = thb[i][r] + MARGIN;
                    if (r4[i][r] < th) {
                        #pragma unroll
                        for (int c = 0; c < 4; ++c)
                            cnt += (fmaf(-2.f, acc[i][c][r], t2v[c]) < th) ? 1u : 0u;
                    }
                }
            u32 pre = cnt;
            #pragma unroll
            for (int d = 1; d < 64; d <<= 1) {
                u32 v = __shfl_up(pre, d, 64);
                if (L >= d) pre += v;
            }
            u32 total = __shfl(pre, 63, 64);

            if (cnt_lds + total <= CBUF) {
                // ---- fast path: emit into LDS buffer ----
                u32 woff = cnt_lds + pre - cnt;
                #pragma unroll
                for (int i = 0; i < 4; ++i)
                    #pragma unroll
                    for (int r = 0; r < 4; ++r) {
                        float th = thb[i][r] + MARGIN;
                        if (r4[i][r] < th) {
                            const int q = mb * 512 + w * 64 + i * 16 + (L >> 4) * 4 + r;
                            #pragma unroll
                            for (int c = 0; c < 4; ++c) {
                                float s = fmaf(-2.f, acc[i][c][r], t2v[c]);
                                if (s < th) {
                                    cbuf[w][woff] = ((u64)__float_as_uint(s) << 32)
                                                  | (u64)(((u32)q << 16) | (u32)(colb + c * 16));
                                    woff++;
                                }
                            }
                        }
                    }
                cnt_lds += total;
                // flush full 64-groups as coalesced 512 B lines
                u32 ngrp = cnt_lds >> 6;
                for (u32 g = 0; g < ngrp; ++g) {
                    u64 v = cbuf[w][g * 64 + L];
                    if (gcur + 64 <= WCAP) wreg[gcur + L] = v;
                    gcur += 64;
                }
                u32 rem = cnt_lds & 63;
                if (ngrp && rem) {
                    u64 v = (L < rem) ? cbuf[w][ngrp * 64 + L] : 0;
                    if (L < rem) cbuf[w][L] = v;
                }
                cnt_lds = rem;
            } else {
                // ---- slow path (rare over-producing tile): drain LDS then direct scatter ----
                u32 ngrp = cnt_lds >> 6;
                for (u32 g = 0; g < ngrp; ++g) {
                    u64 v = cbuf[w][g * 64 + L];
                    if (gcur + 64 <= WCAP) wreg[gcur + L] = v;
                    gcur += 64;
                }
                u32 rem = cnt_lds & 63;
                if (rem) {
                    if (L < rem) {
                        u64 v = cbuf[w][ngrp * 64 + L];
                        if (gcur + L < WCAP) wreg[gcur + L] = v;
                    }
                    gcur += rem;
                }
                cnt_lds = 0;
                u32 woff = gcur + pre - cnt;
                #pragma unroll
                for (int i = 0; i < 4; ++i)
                    #pragma unroll
                    for (int r = 0; r < 4; ++r) {
                        float th = thb[i][r] + MARGIN;
                        if (r4[i][r] < th) {
                            const int q = mb * 512 + w * 64 + i * 16 + (L >> 4) * 4 + r;
                            #pragma unroll
                            for (int c = 0; c < 4; ++c) {
                                float s = fmaf(-2.f, acc[i][c][r], t2v[c]);
                                if (s < th) {
                                    if (woff < WCAP)
                                        wreg[woff] = ((u64)__float_as_uint(s) << 32)
                                                   | (u64)(((u32)q << 16) | (u32)(colb + c * 16));
                                    woff++;
                                }
                            }
                        }
                    }
                gcur += total;
            }
        }

        // fold per-lane; 16-lane butterfly every 2nd tile (tight thresholds, low DS load)
        #pragma unroll
        for (int i = 0; i < 4; ++i)
            #pragma unroll
            for (int r = 0; r < 4; ++r)
                rowmin_reg[i][r] = fminf(rowmin_reg[i][r], r4[i][r]);
        if (((nt - t0) & 1) == 1) {
            #pragma unroll
            for (int st = 1; st <= 8; st <<= 1)
                #pragma unroll
                for (int i = 0; i < 4; ++i)
                    #pragma unroll
                    for (int r = 0; r < 4; ++r)
                        rowmin_reg[i][r] = fminf(rowmin_reg[i][r], __shfl_xor(rowmin_reg[i][r], st, 64));
        }

        __syncthreads();   // drains next-tile stage + protects buffer reuse
    }

    // ---- final flush of LDS candidate remainder ----
    {
        u32 ngrp = cnt_lds >> 6;
        for (u32 g = 0; g < ngrp; ++g) {
            u64 v = cbuf[w][g * 64 + L];
            if (gcur + 64 <= WCAP) wreg[gcur + L] = v;
            gcur += 64;
        }
        u32 rem = cnt_lds & 63;
        if (rem) {
            if (L < rem) {
                u64 v = cbuf[w][ngrp * 64 + L];
                if (gcur + L < WCAP) wreg[gcur + L] = v;
            }
            gcur += rem;
        }
    }

    // ---- final: exact chunk row-min + candidate count ----
    #pragma unroll
    for (int st = 1; st <= 8; st <<= 1)
        #pragma unroll
        for (int i = 0; i < 4; ++i)
            #pragma unroll
            for (int r = 0; r < 4; ++r)
                rowmin_reg[i][r] = fminf(rowmin_reg[i][r], __shfl_xor(rowmin_reg[i][r], st, 64));
    if ((L & 15) == 0) {
        #pragma unroll
        for (int i = 0; i < 4; ++i)
            #pragma unroll
            for (int r = 0; r < 4; ++r) {
                int q = mb * 512 + w * 64 + i * 16 + (L >> 4) * 4 + r;
                chunkmin[(size_t)q * nch + chunk] = rowmin_reg[i][r];
            }
    }
    if (L == 0) wavecnt[gwave] = (gcur < WCAP) ? gcur : WCAP;
    #undef TBASE
}

// ---------------- global bf16 row-min: gmin[q] = min over chunks ----------------
__global__ void reduce_gmin(const float* __restrict__ chunkmin, float* __restrict__ gmin,
                            int B, int nch) {
    const int q = blockIdx.x * 4 + (threadIdx.x >> 6);
    const int c = threadIdx.x & 63;
    if (q >= B) return;
    float v = (c < nch) ? chunkmin[(size_t)q * nch + c] : 1e30f;
    #pragma unroll
    for (int st = 1; st < 64; st <<= 1) v = fminf(v, __shfl_xor(v, st, 64));
    if (c == 0) gmin[q] = v;
}

// ---------------- filtered exact fp32 rescore: ballot-compacted, wave-cooperative ----------------
__global__ void rescore(const float* __restrict__ x, const float* __restrict__ Xt,
                        const float* __restrict__ t2, const float* __restrict__ gmin,
                        const u32* __restrict__ wavecnt, const u64* __restrict__ cands,
                        u64* __restrict__ best) {
    const int L = threadIdx.x & 63;
    const int gw = blockIdx.x * (blockDim.x >> 6) + (threadIdx.x >> 6);
    if (gw >= NWAVE_CAP) return;
    u32 cnt = wavecnt[gw];
    if (cnt > WCAP) cnt = WCAP;
    const u64* reg = cands + (size_t)gw * WCAP;
    for (u32 base = 0; base < cnt; base += 64) {
        u32 i = base + L;
        u64 rec = 0; bool pass = false;
        if (i < cnt) {
            rec = reg[i];                                   // coalesced 512 B
            float sb = __uint_as_float((u32)(rec >> 32));
            int q = (int)((rec >> 16) & 0xFFFFu);
            pass = sb < gmin[q] + FMARGIN;
        }
        u64 bal = __ballot(pass);
        while (bal) {
            int j = __ffsll((unsigned long long)bal) - 1;
            bal &= bal - 1;
            u64 r2 = __shfl(rec, j, 64);
            int q = (int)((r2 >> 16) & 0xFFFFu);
            int n = (int)(r2 & 0xFFFFu);
            float4 a = *((const float4*)(x  + (size_t)q * F_DIM) + L);
            float4 b = *((const float4*)(Xt + (size_t)n * F_DIM) + L);
            float d = fmaf(a.x, b.x, fmaf(a.y, b.y, fmaf(a.z, b.z, a.w * b.w)));
            #pragma unroll
            for (int st = 32; st > 0; st >>= 1) d += __shfl_xor(d, st, 64);
            if (L == 0) {
                float s = fmaf(-2.f, d, t2[n]);
                u64 p = ((u64)ordf(s) << 32) | (u32)n;
                atomicMin(&best[q], p);
            }
        }
    }
}

// ---------------- gather Y[nearest] ----------------
__global__ void gather_kernel(const float* __restrict__ Y, const u64* __restrict__ best,
                              float* __restrict__ out, int B, int N) {
    int gid = blockIdx.x * blockDim.x + threadIdx.x;
    int total = B * O_DIM;
    if (gid >= total) return;
    int b = gid / O_DIM;
    int o = gid - b * O_DIM;
    u32 n = (u32)(best[b] & 0xFFFFFFFFull);
    if (n >= (u32)N) n = 0;   // defensive
    out[gid] = Y[(size_t)n * O_DIM + o];
}

// ================= fp32 fallback (proven Round-1 path, used if ws too small) =================
#define BM 128
#define BN 128
#define BK 16
#define NSPLIT 64
#define LDA (BM + 4)

__global__ __launch_bounds__(256) void knn_main_fp32(
    const float* __restrict__ Xq, const float* __restrict__ Xt,
    const float* __restrict__ t2, u64* __restrict__ best, int N)
{
    __shared__ float As[BK][LDA];
    __shared__ float Bs[BK][LDA];
    __shared__ u64 red[BM][17];

    const int tid = threadIdx.x;
    const int tx = tid & 15;
    const int ty = tid >> 4;
    const int m0 = blockIdx.y * BM;
    const int CHUNK = (N + NSPLIT - 1) / NSPLIT;
    const int n0c = blockIdx.x * CHUNK;
    const int n1c = min(N, n0c + CHUNK);

    u64 bestv[8];
    #pragma unroll
    for (int i = 0; i < 8; ++i) bestv[i] = ~0ull;

    const int srow = tid >> 2;
    const int scol4 = (tid & 3) * 4;

    for (int nt = n0c; nt < n1c; nt += BN) {
        float accl[8][8];
        #pragma unroll
        for (int i = 0; i < 8; ++i)
            #pragma unroll
            for (int j = 0; j < 8; ++j) accl[i][j] = 0.f;
        for (int k0 = 0; k0 < F_DIM; k0 += BK) {
            #pragma unroll
            for (int h = 0; h < 2; ++h) {
                int row = h * 64 + srow;
                float4 av = *(const float4*)(Xq + (size_t)(m0 + row) * F_DIM + k0 + scol4);
                As[scol4 + 0][row] = av.x; As[scol4 + 1][row] = av.y;
                As[scol4 + 2][row] = av.z; As[scol4 + 3][row] = av.w;
                int n = nt + row;
                float4 bv = make_float4(0.f, 0.f, 0.f, 0.f);
                if (n < n1c) bv = *(const float4*)(Xt + (size_t)n * F_DIM + k0 + scol4);
                Bs[scol4 + 0][row] = bv.x; Bs[scol4 + 1][row] = bv.y;
                Bs[scol4 + 2][row] = bv.z; Bs[scol4 + 3][row] = bv.w;
            }
            __syncthreads();
            #pragma unroll
            for (int k = 0; k < BK; ++k) {
                float4 a0 = *(const float4*)&As[k][ty * 4];
                float4 a1 = *(const float4*)&As[k][64 + ty * 4];
                float4 b0 = *(const float4*)&Bs[k][tx * 4];
                float4 b1 = *(const float4*)&Bs[k][64 + tx * 4];
                float am[8] = {a0.x, a0.y, a0.z, a0.w, a1.x, a1.y, a1.z, a1.w};
                float bn[8] = {b0.x, b0.y, b0.z, b0.w, b1.x, b1.y, b1.z, b1.w};
                #pragma unroll
                for (int i = 0; i < 8; ++i)
                    #pragma unroll
                    for (int j = 0; j < 8; ++j)
                        accl[i][j] = fmaf(am[i], bn[j], accl[i][j]);
            }
            __syncthreads();
        }
        #pragma unroll
        for (int j = 0; j < 8; ++j) {
            int nl = (j < 4) ? (tx * 4 + j) : (64 + tx * 4 + (j - 4));
            int n = nt + nl;
            if (n < n1c) {
                float t2v = t2[n];
                #pragma unroll
                for (int i = 0; i < 8; ++i) {
                    float score = fmaf(-2.f, accl[i][j], t2v);
                    u64 p = ((u64)ordf(score) << 32) | (u32)n;
                    bestv[i] = (p < bestv[i]) ? p : bestv[i];
                }
            }
        }
    }
    #pragma unroll
    for (int i = 0; i < 8; ++i) {
        int ml = (i < 4) ? (ty * 4 + i) : (64 + ty * 4 + (i - 4));
        red[ml][tx] = bestv[i];
    }
    __syncthreads();
    if (tid < BM) {
        u64 b = red[tid][0];
        #pragma unroll
        for (int t = 1; t < 16; ++t) { u64 v = red[tid][t]; b = (v < b) ? v : b; }
        atomicMin(&best[m0 + tid], b);
    }
}

// ================= launch =================
extern "C" void kernel_launch(void* const* d_in, const int* in_sizes, int n_in,
                              void* d_out, int out_size, void* d_ws, size_t ws_size,
                              hipStream_t stream) {
    const float* x  = (const float*)d_in[0];
    const float* Xt = (const float*)d_in[1];
    const float* Yt = (const float*)d_in[2];
    float* out = (float*)d_out;

    const int B = in_sizes[0] / F_DIM;        // 2048
    const int N = in_sizes[1] / F_DIM;        // 50000
    const int NT128 = (N + 127) / 128;        // 391
    const int Npad = NT128 * 128;             // 50048
    const int NT64 = NT128 * 2;               // 782
    const int MB = B / 512;                   // 4
    const int MT128 = B / 128;                // 16
    const int NCH = 64;                       // 4*64 = 256 blocks = 1/CU

    char* wsp = (char*)d_ws;
    size_t off = 0;
    auto nxt = [&](size_t bytes) {
        char* p = wsp + off;
        off = (off + bytes + 255) & ~(size_t)255;
        return p;
    };
    float* t2       = (float*)nxt((size_t)Npad * 4);
    u64*   best     = (u64*)  nxt((size_t)B * 8);
    u32*   wavecnt  = (u32*)  nxt((size_t)NWAVE_CAP * 4);
    float* gmin     = (float*)nxt((size_t)B * 4);
    float* chunkmin = (float*)nxt((size_t)B * NCH * 4);
    u64*   cands    = (u64*)  nxt((size_t)NWAVE_CAP * WCAP * 8);
    u16*   xbf      = (u16*)  nxt((size_t)B * F_DIM * 2);
    u16*   xtbf     = (u16*)  nxt((size_t)Npad * F_DIM * 2);
    size_t required = off;

    init_kernel<<<(B + 255) / 256, 256, 0, stream>>>(best, B);

    if (ws_size >= required && B % 512 == 0 && MB * NCH * 8 <= NWAVE_CAP) {
        convert_tile<<<dim3(MT128, 4), 256, 0, stream>>>(x, xbf, (float*)nullptr, B, 0);
        convert_tile<<<dim3(NT128, 4), 256, 0, stream>>>(Xt, xtbf, t2, N, 1);   // fused t2
        knn_mfma<<<MB * NCH, 512, 0, stream>>>(xbf, xtbf, t2, chunkmin, wavecnt, cands, NT64, NCH);
        reduce_gmin<<<(B + 3) / 4, 256, 0, stream>>>(chunkmin, gmin, B, NCH);
        rescore<<<NWAVE_CAP / 4, 256, 0, stream>>>(x, Xt, t2, gmin, wavecnt, cands, best);
    } else {
        t2_kernel<<<(N + 3) / 4, 256, 0, stream>>>(Xt, t2, N, N);
        dim3 grid(NSPLIT, B / BM);
        knn_main_fp32<<<grid, 256, 0, stream>>>(x, Xt, t2, best, N);
    }

    int total = B * O_DIM;
    gather_kernel<<<(total + 255) / 256, 256, 0, stream>>>(Yt, best, out, B, N);
}

// Round 12
// 297.175 us; speedup vs baseline: 1.1568x; 1.1568x over previous
//
#include <hip/hip_runtime.h>
#include <stdint.h>

typedef unsigned short u16;
typedef unsigned int   u32;
typedef unsigned long long u64;

#define F_DIM 256
#define O_DIM 24
#define MARGIN  3.0f      // capture margin (>= 2E bf16-vs-fp32 score bound; validated R2-R11)
#define FMARGIN 3.0f      // rescore global filter margin (same bound)
#define WCAP 1536         // candidate slots per capture-wave (8 B each)
#define NWAVE_CAP 2048    // 4 mb * 64 chunks * 8 waves

#define AS1 __attribute__((address_space(1)))
#define AS3 __attribute__((address_space(3)))

typedef __bf16 bf16x8 __attribute__((ext_vector_type(8)));
typedef float  f32x4  __attribute__((ext_vector_type(4)));

__device__ __forceinline__ u32 ordf(float s) {
    u32 b = __float_as_uint(s);
    return (b & 0x80000000u) ? ~b : (b | 0x80000000u);
}
__device__ __forceinline__ u16 f2bf(float f) {   // round-to-nearest-even
    u32 u = __float_as_uint(f);
    u32 r = (u + 0x7FFFu + ((u >> 16) & 1u)) >> 16;
    return (u16)r;
}

// ---------------- init ----------------
__global__ void init_kernel(u64* best, int B) {
    int i = blockIdx.x * blockDim.x + threadIdx.x;
    if (i < B) best[i] = ~0ull;
}

// ---------------- t2 (fallback path only) ----------------
__global__ void t2_kernel(const float* __restrict__ X, float* __restrict__ t2,
                          int N, int Npad) {
    int tid = threadIdx.x;
    int row = blockIdx.x * 4 + (tid >> 6);
    int lane = tid & 63;
    if (row >= Npad) return;
    if (row >= N) { if (lane == 0) t2[row] = 1e30f; return; }
    float4 v = ((const float4*)(X + (size_t)row * F_DIM))[lane];
    float s = v.x * v.x + v.y * v.y + v.z * v.z + v.w * v.w;
    #pragma unroll
    for (int off = 32; off > 0; off >>= 1) s += __shfl_down(s, off, 64);
    if (lane == 0) t2[row] = s;
}

// ---------------- coalesced converter: fp32 row-major -> bf16 fragment order ----------------
__global__ __launch_bounds__(256) void convert_tile(const float* __restrict__ src,
        u16* __restrict__ dst, float* __restrict__ t2out, int nrows, int do_t2) {
    __shared__ u16 tl[8192];   // 16 KB
    const int tid = threadIdx.x;
    const int t = blockIdx.x, p = blockIdx.y;
    const int w = tid >> 6, L = tid & 63;
    const int col = L * 4;
    const int ks = col >> 5, j = col & 7, lhi = ((col >> 3) & 3) << 4;
    #pragma unroll
    for (int i = 0; i < 8; ++i) {
        int rloc = i * 4 + w;
        int grow = t * 128 + p * 32 + rloc;
        float4 v = make_float4(0.f, 0.f, 0.f, 0.f);
        if (grow < nrows) v = *(const float4*)(src + (size_t)grow * F_DIM + col);
        if (do_t2) {
            float s = v.x * v.x + v.y * v.y + v.z * v.z + v.w * v.w;
            #pragma unroll
            for (int off = 32; off > 0; off >>= 1) s += __shfl_down(s, off, 64);
            if (L == 0) t2out[grow] = (grow < nrows) ? s : 1e30f;
        }
        u16* q = &tl[ks * 1024 + (rloc >> 4) * 512 + (((rloc & 15) | lhi)) * 8 + j];
        q[0] = f2bf(v.x); q[1] = f2bf(v.y); q[2] = f2bf(v.z); q[3] = f2bf(v.w);
    }
    __syncthreads();
    const uint4* s4 = (const uint4*)tl;
    uint4* d4 = (uint4*)(dst + (size_t)t * 32768);
    #pragma unroll
    for (int v = 0; v < 4; ++v) {
        int lin = v * 256 + tid;
        int ksc = lin >> 7, subl = (lin >> 6) & 1, lane = lin & 63;
        d4[(ksc * 8 + 2 * p + subl) * 64 + lane] = s4[lin];
    }
}

// ---------------- main: M=512 LDS-shared bf16 MFMA, every-tile butterfly thresholds ----------------
__global__ __launch_bounds__(512, 2) void knn_mfma(
    const u16* __restrict__ xbf, const u16* __restrict__ xtbf,
    const float* __restrict__ t2, float* __restrict__ chunkmin,
    u32* __restrict__ wavecnt, u64* __restrict__ cands,
    int ntiles /*64-col tiles*/, int nch)
{
    __shared__ u16 sB[2][16384];   // 2 x 32 KB

    const int tid = threadIdx.x;
    const int L = tid & 63, w = tid >> 6;     // 8 waves
    const int id = blockIdx.x;
    const int slot = id & 7, rest = id >> 3;
    const int mb = rest & 3;                  // 512-row m-block
    const int chunk = slot + 8 * (rest >> 2); // 0..63
    const int gwave = ((mb << 6) | chunk) * 8 + w;
    const int t0 = (int)(((long long)chunk * ntiles) / nch);
    const int t1 = (int)(((long long)(chunk + 1) * ntiles) / nch);

    #define TBASE(nt) (xtbf + ((size_t)((nt) >> 1)) * 32768 + (size_t)((nt) & 1) * 2048)

    // ---- stage first B tile (async, 4 rounds x 512 threads x 16 B = 32 KB) ----
    {
        const u16* tb = TBASE(t0);
        const int ksq_half = tid >> 8;
        const int inner = tid & 255;
        #pragma unroll
        for (int r = 0; r < 4; ++r) {
            int ksq = r * 2 + ksq_half;
            __builtin_amdgcn_global_load_lds(
                (const AS1 u32*)(tb + ksq * 4096 + inner * 8),
                (AS3 u32*)&sB[0][0] + ksq * 1024 + inner * 4, 16, 0, 0);
        }
    }

    // ---- A fragments in registers: wave w owns rows mb*512 + w*64 .. +63 ----
    bf16x8 areg[32];
    {
        const int t128 = mb * 4 + (w >> 1);
        const u16* base = xbf + (size_t)t128 * 32768 + (size_t)((w & 1) * 4) * 512 + (size_t)L * 8;
        #pragma unroll
        for (int ks = 0; ks < 8; ++ks)
            #pragma unroll
            for (int i = 0; i < 4; ++i)
                areg[ks * 4 + i] = *(const bf16x8*)(base + ks * 4096 + i * 512);
    }

    float rowmin_reg[4][4];
    #pragma unroll
    for (int i = 0; i < 4; ++i)
        #pragma unroll
        for (int r = 0; r < 4; ++r) rowmin_reg[i][r] = 1e30f;

    u32 wcount = 0;
    u64* const wreg = cands + (size_t)gwave * WCAP;

    __syncthreads();   // first B tile staged

    for (int nt = t0; nt < t1; ++nt) {
        const int cur = (nt - t0) & 1;
        if (nt + 1 < t1) {   // stage next tile into other buffer (drains at end barrier)
            const u16* tb = TBASE(nt + 1);
            const int ksq_half = tid >> 8;
            const int inner = tid & 255;
            #pragma unroll
            for (int r = 0; r < 4; ++r) {
                int ksq = r * 2 + ksq_half;
                __builtin_amdgcn_global_load_lds(
                    (const AS1 u32*)(tb + ksq * 4096 + inner * 8),
                    (AS3 u32*)&sB[cur ^ 1][0] + ksq * 1024 + inner * 4, 16, 0, 0);
            }
        }

        float t2v[4];
        #pragma unroll
        for (int c = 0; c < 4; ++c) t2v[c] = t2[nt * 64 + (L & 15) + c * 16];

        f32x4 acc[4][4];
        #pragma unroll
        for (int i = 0; i < 4; ++i)
            #pragma unroll
            for (int c = 0; c < 4; ++c)
                #pragma unroll
                for (int r = 0; r < 4; ++r) acc[i][c][r] = 0.f;

        #pragma unroll
        for (int ks = 0; ks < 8; ++ks) {
            bf16x8 bc[4];
            #pragma unroll
            for (int c = 0; c < 4; ++c)
                bc[c] = *(const bf16x8*)&sB[cur][ks * 2048 + c * 512 + L * 8];
            #pragma unroll
            for (int i = 0; i < 4; ++i)
                #pragma unroll
                for (int c = 0; c < 4; ++c)
                    acc[i][c] = __builtin_amdgcn_mfma_f32_16x16x32_bf16(areg[ks * 4 + i], bc[c], acc[i][c], 0, 0, 0);
        }

        // ---- epilogue ----
        const int colb = nt * 64 + (L & 15);
        float r4[4][4];
        #pragma unroll
        for (int i = 0; i < 4; ++i) {
            #pragma unroll
            for (int r = 0; r < 4; ++r) r4[i][r] = 1e30f;
            #pragma unroll
            for (int c = 0; c < 4; ++c)
                #pragma unroll
                for (int r = 0; r < 4; ++r)
                    r4[i][r] = fminf(r4[i][r], fmaf(-2.f, acc[i][c][r], t2v[c]));
        }

        // threshold base: true running row-min (butterflied every tile) folded with
        // this tile's lane view — subset-min of the row's bf16 scores, safe w/ MARGIN>=2E
        float thb[4][4];
        if (nt == t0) {
            // seed: butterfly tile-t0 row-min FIRST so t0 capture doesn't flood
            #pragma unroll
            for (int i = 0; i < 4; ++i)
                #pragma unroll
                for (int r = 0; r < 4; ++r) rowmin_reg[i][r] = r4[i][r];
            #pragma unroll
            for (int st = 1; st <= 8; st <<= 1)
                #pragma unroll
                for (int i = 0; i < 4; ++i)
                    #pragma unroll
                    for (int r = 0; r < 4; ++r)
                        rowmin_reg[i][r] = fminf(rowmin_reg[i][r], __shfl_xor(rowmin_reg[i][r], st, 64));
            #pragma unroll
            for (int i = 0; i < 4; ++i)
                #pragma unroll
                for (int r = 0; r < 4; ++r) thb[i][r] = rowmin_reg[i][r];
        } else {
            #pragma unroll
            for (int i = 0; i < 4; ++i)
                #pragma unroll
                for (int r = 0; r < 4; ++r) thb[i][r] = fminf(rowmin_reg[i][r], r4[i][r]);
        }

        bool anyhit = false;
        #pragma unroll
        for (int i = 0; i < 4; ++i)
            #pragma unroll
            for (int r = 0; r < 4; ++r)
                anyhit = anyhit || (r4[i][r] < thb[i][r] + MARGIN);

        if (__any(anyhit)) {
            u32 cnt = 0;
            #pragma unroll
            for (int i = 0; i < 4; ++i)
                #pragma unroll
                for (int r = 0; r < 4; ++r) {
                    float th = thb[i][r] + MARGIN;
                    if (r4[i][r] < th) {
                        #pragma unroll
                        for (int c = 0; c < 4; ++c)
                            cnt += (fmaf(-2.f, acc[i][c][r], t2v[c]) < th) ? 1u : 0u;
                    }
                }
            u32 pre = cnt;
            #pragma unroll
            for (int d = 1; d < 64; d <<= 1) {
                u32 v = __shfl_up(pre, d, 64);
                if (L >= d) pre += v;
            }
            u32 total = __shfl(pre, 63, 64);
            u32 woff = wcount + pre - cnt;
            #pragma unroll
            for (int i = 0; i < 4; ++i)
                #pragma unroll
                for (int r = 0; r < 4; ++r) {
                    float th = thb[i][r] + MARGIN;
                    if (r4[i][r] < th) {
                        const int q = mb * 512 + w * 64 + i * 16 + (L >> 4) * 4 + r;
                        #pragma unroll
                        for (int c = 0; c < 4; ++c) {
                            float s = fmaf(-2.f, acc[i][c][r], t2v[c]);
                            if (s < th) {
                                if (woff < WCAP)
                                    wreg[woff] = ((u64)__float_as_uint(s) << 32)
                                               | (u64)(((u32)q << 16) | (u32)(colb + c * 16));
                                woff++;
                            }
                        }
                    }
                }
            wcount += total;
        }

        // fold per-lane + full 16-lane butterfly EVERY tile -> tightest thresholds
        #pragma unroll
        for (int i = 0; i < 4; ++i)
            #pragma unroll
            for (int r = 0; r < 4; ++r)
                rowmin_reg[i][r] = fminf(rowmin_reg[i][r], r4[i][r]);
        #pragma unroll
        for (int st = 1; st <= 8; st <<= 1)
            #pragma unroll
            for (int i = 0; i < 4; ++i)
                #pragma unroll
                for (int r = 0; r < 4; ++r)
                    rowmin_reg[i][r] = fminf(rowmin_reg[i][r], __shfl_xor(rowmin_reg[i][r], st, 64));

        __syncthreads();   // drains next-tile stage + protects buffer reuse
    }

    // ---- final: exact chunk row-min + candidate count ----
    if ((L & 15) == 0) {
        #pragma unroll
        for (int i = 0; i < 4; ++i)
            #pragma unroll
            for (int r = 0; r < 4; ++r) {
                int q = mb * 512 + w * 64 + i * 16 + (L >> 4) * 4 + r;
                chunkmin[(size_t)q * nch + chunk] = rowmin_reg[i][r];
            }
    }
    if (L == 0) wavecnt[gwave] = (wcount < WCAP) ? wcount : WCAP;
    #undef TBASE
}

// ---------------- global bf16 row-min: gmin[q] = min over chunks ----------------
__global__ void reduce_gmin(const float* __restrict__ chunkmin, float* __restrict__ gmin,
                            int B, int nch) {
    const int q = blockIdx.x * 4 + (threadIdx.x >> 6);
    const int c = threadIdx.x & 63;
    if (q >= B) return;
    float v = (c < nch) ? chunkmin[(size_t)q * nch + c] : 1e30f;
    #pragma unroll
    for (int st = 1; st < 64; st <<= 1) v = fminf(v, __shfl_xor(v, st, 64));
    if (c == 0) gmin[q] = v;
}

// ---------------- filtered exact fp32 rescore: ballot-compacted, wave-cooperative ----------------
__global__ void rescore(const float* __restrict__ x, const float* __restrict__ Xt,
                        const float* __restrict__ t2, const float* __restrict__ gmin,
                        const u32* __restrict__ wavecnt, const u64* __restrict__ cands,
                        u64* __restrict__ best) {
    const int L = threadIdx.x & 63;
    const int gw = blockIdx.x * (blockDim.x >> 6) + (threadIdx.x >> 6);
    if (gw >= NWAVE_CAP) return;
    u32 cnt = wavecnt[gw];
    if (cnt > WCAP) cnt = WCAP;
    const u64* reg = cands + (size_t)gw * WCAP;
    for (u32 base = 0; base < cnt; base += 64) {
        u32 i = base + L;
        u64 rec = 0; bool pass = false;
        if (i < cnt) {
            rec = reg[i];                                   // coalesced 512 B
            float sb = __uint_as_float((u32)(rec >> 32));
            int q = (int)((rec >> 16) & 0xFFFFu);
            pass = sb < gmin[q] + FMARGIN;
        }
        u64 bal = __ballot(pass);
        while (bal) {
            int j = __ffsll((unsigned long long)bal) - 1;
            bal &= bal - 1;
            u64 r2 = __shfl(rec, j, 64);
            int q = (int)((r2 >> 16) & 0xFFFFu);
            int n = (int)(r2 & 0xFFFFu);
            float4 a = *((const float4*)(x  + (size_t)q * F_DIM) + L);
            float4 b = *((const float4*)(Xt + (size_t)n * F_DIM) + L);
            float d = fmaf(a.x, b.x, fmaf(a.y, b.y, fmaf(a.z, b.z, a.w * b.w)));
            #pragma unroll
            for (int st = 32; st > 0; st >>= 1) d += __shfl_xor(d, st, 64);
            if (L == 0) {
                float s = fmaf(-2.f, d, t2[n]);
                u64 p = ((u64)ordf(s) << 32) | (u32)n;
                atomicMin(&best[q], p);
            }
        }
    }
}

// ---------------- gather Y[nearest] ----------------
__global__ void gather_kernel(const float* __restrict__ Y, const u64* __restrict__ best,
                              float* __restrict__ out, int B, int N) {
    int gid = blockIdx.x * blockDim.x + threadIdx.x;
    int total = B * O_DIM;
    if (gid >= total) return;
    int b = gid / O_DIM;
    int o = gid - b * O_DIM;
    u32 n = (u32)(best[b] & 0xFFFFFFFFull);
    if (n >= (u32)N) n = 0;   // defensive
    out[gid] = Y[(size_t)n * O_DIM + o];
}

// ================= fp32 fallback (proven Round-1 path, used if ws too small) =================
#define BM 128
#define BN 128
#define BK 16
#define NSPLIT 64
#define LDA (BM + 4)

__global__ __launch_bounds__(256) void knn_main_fp32(
    const float* __restrict__ Xq, const float* __restrict__ Xt,
    const float* __restrict__ t2, u64* __restrict__ best, int N)
{
    __shared__ float As[BK][LDA];
    __shared__ float Bs[BK][LDA];
    __shared__ u64 red[BM][17];

    const int tid = threadIdx.x;
    const int tx = tid & 15;
    const int ty = tid >> 4;
    const int m0 = blockIdx.y * BM;
    const int CHUNK = (N + NSPLIT - 1) / NSPLIT;
    const int n0c = blockIdx.x * CHUNK;
    const int n1c = min(N, n0c + CHUNK);

    u64 bestv[8];
    #pragma unroll
    for (int i = 0; i < 8; ++i) bestv[i] = ~0ull;

    const int srow = tid >> 2;
    const int scol4 = (tid & 3) * 4;

    for (int nt = n0c; nt < n1c; nt += BN) {
        float accl[8][8];
        #pragma unroll
        for (int i = 0; i < 8; ++i)
            #pragma unroll
            for (int j = 0; j < 8; ++j) accl[i][j] = 0.f;
        for (int k0 = 0; k0 < F_DIM; k0 += BK) {
            #pragma unroll
            for (int h = 0; h < 2; ++h) {
                int row = h * 64 + srow;
                float4 av = *(const float4*)(Xq + (size_t)(m0 + row) * F_DIM + k0 + scol4);
                As[scol4 + 0][row] = av.x; As[scol4 + 1][row] = av.y;
                As[scol4 + 2][row] = av.z; As[scol4 + 3][row] = av.w;
                int n = nt + row;
                float4 bv = make_float4(0.f, 0.f, 0.f, 0.f);
                if (n < n1c) bv = *(const float4*)(Xt + (size_t)n * F_DIM + k0 + scol4);
                Bs[scol4 + 0][row] = bv.x; Bs[scol4 + 1][row] = bv.y;
                Bs[scol4 + 2][row] = bv.z; Bs[scol4 + 3][row] = bv.w;
            }
            __syncthreads();
            #pragma unroll
            for (int k = 0; k < BK; ++k) {
                float4 a0 = *(const float4*)&As[k][ty * 4];
                float4 a1 = *(const float4*)&As[k][64 + ty * 4];
                float4 b0 = *(const float4*)&Bs[k][tx * 4];
                float4 b1 = *(const float4*)&Bs[k][64 + tx * 4];
                float am[8] = {a0.x, a0.y, a0.z, a0.w, a1.x, a1.y, a1.z, a1.w};
                float bn[8] = {b0.x, b0.y, b0.z, b0.w, b1.x, b1.y, b1.z, b1.w};
                #pragma unroll
                for (int i = 0; i < 8; ++i)
                    #pragma unroll
                    for (int j = 0; j < 8; ++j)
                        accl[i][j] = fmaf(am[i], bn[j], accl[i][j]);
            }
            __syncthreads();
        }
        #pragma unroll
        for (int j = 0; j < 8; ++j) {
            int nl = (j < 4) ? (tx * 4 + j) : (64 + tx * 4 + (j - 4));
            int n = nt + nl;
            if (n < n1c) {
                float t2v = t2[n];
                #pragma unroll
                for (int i = 0; i < 8; ++i) {
                    float score = fmaf(-2.f, accl[i][j], t2v);
                    u64 p = ((u64)ordf(score) << 32) | (u32)n;
                    bestv[i] = (p < bestv[i]) ? p : bestv[i];
                }
            }
        }
    }
    #pragma unroll
    for (int i = 0; i < 8; ++i) {
        int ml = (i < 4) ? (ty * 4 + i) : (64 + ty * 4 + (i - 4));
        red[ml][tx] = bestv[i];
    }
    __syncthreads();
    if (tid < BM) {
        u64 b = red[tid][0];
        #pragma unroll
        for (int t = 1; t < 16; ++t) { u64 v = red[tid][t]; b = (v < b) ? v : b; }
        atomicMin(&best[m0 + tid], b);
    }
}

// ================= launch =================
extern "C" void kernel_launch(void* const* d_in, const int* in_sizes, int n_in,
                              void* d_out, int out_size, void* d_ws, size_t ws_size,
                              hipStream_t stream) {
    const float* x  = (const float*)d_in[0];
    const float* Xt = (const float*)d_in[1];
    const float* Yt = (const float*)d_in[2];
    float* out = (float*)d_out;

    const int B = in_sizes[0] / F_DIM;        // 2048
    const int N = in_sizes[1] / F_DIM;        // 50000
    const int NT128 = (N + 127) / 128;        // 391
    const int Npad = NT128 * 128;             // 50048
    const int NT64 = NT128 * 2;               // 782
    const int MB = B / 512;                   // 4
    const int MT128 = B / 128;                // 16
    const int NCH = 64;                       // 4*64 = 256 blocks = 1/CU

    char* wsp = (char*)d_ws;
    size_t off = 0;
    auto nxt = [&](size_t bytes) {
        char* p = wsp + off;
        off = (off + bytes + 255) & ~(size_t)255;
        return p;
    };
    float* t2       = (float*)nxt((size_t)Npad * 4);
    u64*   best     = (u64*)  nxt((size_t)B * 8);
    u32*   wavecnt  = (u32*)  nxt((size_t)NWAVE_CAP * 4);
    float* gmin     = (float*)nxt((size_t)B * 4);
    float* chunkmin = (float*)nxt((size_t)B * NCH * 4);
    u64*   cands    = (u64*)  nxt((size_t)NWAVE_CAP * WCAP * 8);
    u16*   xbf      = (u16*)  nxt((size_t)B * F_DIM * 2);
    u16*   xtbf     = (u16*)  nxt((size_t)Npad * F_DIM * 2);
    size_t required = off;

    init_kernel<<<(B + 255) / 256, 256, 0, stream>>>(best, B);

    if (ws_size >= required && B % 512 == 0 && MB * NCH * 8 <= NWAVE_CAP) {
        convert_tile<<<dim3(MT128, 4), 256, 0, stream>>>(x, xbf, (float*)nullptr, B, 0);
        convert_tile<<<dim3(NT128, 4), 256, 0, stream>>>(Xt, xtbf, t2, N, 1);   // fused t2
        knn_mfma<<<MB * NCH, 512, 0, stream>>>(xbf, xtbf, t2, chunkmin, wavecnt, cands, NT64, NCH);
        reduce_gmin<<<(B + 3) / 4, 256, 0, stream>>>(chunkmin, gmin, B, NCH);
        rescore<<<NWAVE_CAP / 4, 256, 0, stream>>>(x, Xt, t2, gmin, wavecnt, cands, best);
    } else {
        t2_kernel<<<(N + 3) / 4, 256, 0, stream>>>(Xt, t2, N, N);
        dim3 grid(NSPLIT, B / BM);
        knn_main_fp32<<<grid, 256, 0, stream>>>(x, Xt, t2, best, N);
    }

    int total = B * O_DIM;
    gather_kernel<<<(total + 255) / 256, 256, 0, stream>>>(Yt, best, out, B, N);
}

// Round 13
// 296.420 us; speedup vs baseline: 1.1597x; 1.0025x over previous
//
#include <hip/hip_runtime.h>
#include <stdint.h>

typedef unsigned short u16;
typedef unsigned int   u32;
typedef unsigned long long u64;

#define F_DIM 256
#define O_DIM 24
#define MARGIN  3.0f      // capture margin (>= 2E bf16-vs-fp32 score bound; validated R2-R12)
#define FMARGIN 3.0f      // rescore global filter margin (same bound)
#define WCAP 1536         // candidate slots per capture-wave (8 B each)
#define NWAVE_CAP 2048    // 8 mb * 64 chunks * 4 waves

#define AS1 __attribute__((address_space(1)))
#define AS3 __attribute__((address_space(3)))

typedef __bf16 bf16x8 __attribute__((ext_vector_type(8)));
typedef float  f32x4  __attribute__((ext_vector_type(4)));

__device__ __forceinline__ u32 ordf(float s) {
    u32 b = __float_as_uint(s);
    return (b & 0x80000000u) ? ~b : (b | 0x80000000u);
}
__device__ __forceinline__ u16 f2bf(float f) {   // round-to-nearest-even
    u32 u = __float_as_uint(f);
    u32 r = (u + 0x7FFFu + ((u >> 16) & 1u)) >> 16;
    return (u16)r;
}

// ---------------- init ----------------
__global__ void init_kernel(u64* best, int B) {
    int i = blockIdx.x * blockDim.x + threadIdx.x;
    if (i < B) best[i] = ~0ull;
}

// ---------------- t2 (fallback path only) ----------------
__global__ void t2_kernel(const float* __restrict__ X, float* __restrict__ t2,
                          int N, int Npad) {
    int tid = threadIdx.x;
    int row = blockIdx.x * 4 + (tid >> 6);
    int lane = tid & 63;
    if (row >= Npad) return;
    if (row >= N) { if (lane == 0) t2[row] = 1e30f; return; }
    float4 v = ((const float4*)(X + (size_t)row * F_DIM))[lane];
    float s = v.x * v.x + v.y * v.y + v.z * v.z + v.w * v.w;
    #pragma unroll
    for (int off = 32; off > 0; off >>= 1) s += __shfl_down(s, off, 64);
    if (lane == 0) t2[row] = s;
}

// ---------------- coalesced converter: fp32 row-major -> bf16 fragment order ----------------
__global__ __launch_bounds__(256) void convert_tile(const float* __restrict__ src,
        u16* __restrict__ dst, float* __restrict__ t2out, int nrows, int do_t2) {
    __shared__ u16 tl[8192];   // 16 KB
    const int tid = threadIdx.x;
    const int t = blockIdx.x, p = blockIdx.y;
    const int w = tid >> 6, L = tid & 63;
    const int col = L * 4;
    const int ks = col >> 5, j = col & 7, lhi = ((col >> 3) & 3) << 4;
    #pragma unroll
    for (int i = 0; i < 8; ++i) {
        int rloc = i * 4 + w;
        int grow = t * 128 + p * 32 + rloc;
        float4 v = make_float4(0.f, 0.f, 0.f, 0.f);
        if (grow < nrows) v = *(const float4*)(src + (size_t)grow * F_DIM + col);
        if (do_t2) {
            float s = v.x * v.x + v.y * v.y + v.z * v.z + v.w * v.w;
            #pragma unroll
            for (int off = 32; off > 0; off >>= 1) s += __shfl_down(s, off, 64);
            if (L == 0) t2out[grow] = (grow < nrows) ? s : 1e30f;
        }
        u16* q = &tl[ks * 1024 + (rloc >> 4) * 512 + (((rloc & 15) | lhi)) * 8 + j];
        q[0] = f2bf(v.x); q[1] = f2bf(v.y); q[2] = f2bf(v.z); q[3] = f2bf(v.w);
    }
    __syncthreads();
    const uint4* s4 = (const uint4*)tl;
    uint4* d4 = (uint4*)(dst + (size_t)t * 32768);
    #pragma unroll
    for (int v = 0; v < 4; ++v) {
        int lin = v * 256 + tid;
        int ksc = lin >> 7, subl = (lin >> 6) & 1, lane = lin & 63;
        d4[(ksc * 8 + 2 * p + subl) * 64 + lane] = s4[lin];
    }
}

// ---------------- main: R5 geometry (256 thr, M=256, 2 blocks/CU) + tight thresholds ----------------
// grid = dim3(MB=8, NCH=64): consecutive blocks = the 8 mb-partners of one chunk ->
// spread across XCDs; B re-reads absorbed by L3 (R5 measured 131 MB HBM, 121 us).
__global__ __launch_bounds__(256, 2) void knn_mfma(
    const u16* __restrict__ xbf, const u16* __restrict__ xtbf,
    const float* __restrict__ t2, float* __restrict__ chunkmin,
    u32* __restrict__ wavecnt, u64* __restrict__ cands,
    int ntiles /*64-col tiles*/, int nch)
{
    __shared__ u16 sB[2][16384];   // 2 x 32 KB

    const int tid = threadIdx.x;
    const int L = tid & 63, w = tid >> 6;   // 4 waves
    const int mb = blockIdx.x;              // 256-row m-block (8)
    const int chunk = blockIdx.y;           // 64
    const int gwave = (mb * 64 + chunk) * 4 + w;
    const int t0 = (int)(((long long)chunk * ntiles) / nch);
    const int t1 = (int)(((long long)(chunk + 1) * ntiles) / nch);

    #define TBASE_U32(nt) ((const AS1 u32*)xtbf + (size_t)((nt) >> 1) * 16384 + (size_t)((nt) & 1) * 1024)

    // ---- stage first B tile (async, 8 x 256 threads x 16 B = 32 KB) ----
    {
        const AS1 u32* gp = TBASE_U32(t0);
        AS3 u32* lb = (AS3 u32*)&sB[0][0];
        #pragma unroll
        for (int ks = 0; ks < 8; ++ks)
            __builtin_amdgcn_global_load_lds(gp + (size_t)ks * 2048 + (size_t)tid * 4,
                                             lb + ks * 1024 + w * 256, 16, 0, 0);
    }

    // ---- A fragments in registers: wave w owns rows mb*256 + w*64 .. +63 ----
    bf16x8 areg[32];
    {
        const int t128 = mb * 2 + (w >> 1);
        const u16* base = xbf + (size_t)t128 * 32768 + (size_t)((w & 1) * 4) * 512 + (size_t)L * 8;
        #pragma unroll
        for (int ks = 0; ks < 8; ++ks)
            #pragma unroll
            for (int i = 0; i < 4; ++i)
                areg[ks * 4 + i] = *(const bf16x8*)(base + ks * 4096 + i * 512);
    }

    float rowmin_reg[4][4];
    #pragma unroll
    for (int i = 0; i < 4; ++i)
        #pragma unroll
        for (int r = 0; r < 4; ++r) rowmin_reg[i][r] = 1e30f;

    u32 wcount = 0;
    u64* const wreg = cands + (size_t)gwave * WCAP;

    __syncthreads();   // first B tile staged

    for (int nt = t0; nt < t1; ++nt) {
        const int cur = (nt - t0) & 1;
        if (nt + 1 < t1) {   // stage next tile into other buffer (drains at end barrier)
            const AS1 u32* gp = TBASE_U32(nt + 1);
            AS3 u32* lb = (AS3 u32*)&sB[cur ^ 1][0];
            #pragma unroll
            for (int ks = 0; ks < 8; ++ks)
                __builtin_amdgcn_global_load_lds(gp + (size_t)ks * 2048 + (size_t)tid * 4,
                                                 lb + ks * 1024 + w * 256, 16, 0, 0);
        }

        float t2v[4];
        #pragma unroll
        for (int c = 0; c < 4; ++c) t2v[c] = t2[nt * 64 + (L & 15) + c * 16];

        f32x4 acc[4][4];
        #pragma unroll
        for (int i = 0; i < 4; ++i)
            #pragma unroll
            for (int c = 0; c < 4; ++c)
                #pragma unroll
                for (int r = 0; r < 4; ++r) acc[i][c][r] = 0.f;

        #pragma unroll
        for (int ks = 0; ks < 8; ++ks) {
            bf16x8 bc[4];
            #pragma unroll
            for (int c = 0; c < 4; ++c)
                bc[c] = *(const bf16x8*)&sB[cur][ks * 2048 + c * 512 + L * 8];
            #pragma unroll
            for (int i = 0; i < 4; ++i)
                #pragma unroll
                for (int c = 0; c < 4; ++c)
                    acc[i][c] = __builtin_amdgcn_mfma_f32_16x16x32_bf16(areg[ks * 4 + i], bc[c], acc[i][c], 0, 0, 0);
        }

        // ---- epilogue ----
        const int colb = nt * 64 + (L & 15);
        float r4[4][4];
        #pragma unroll
        for (int i = 0; i < 4; ++i) {
            #pragma unroll
            for (int r = 0; r < 4; ++r) r4[i][r] = 1e30f;
            #pragma unroll
            for (int c = 0; c < 4; ++c)
                #pragma unroll
                for (int r = 0; r < 4; ++r)
                    r4[i][r] = fminf(r4[i][r], fmaf(-2.f, acc[i][c][r], t2v[c]));
        }

        // threshold base (subset-min of the row's bf16 scores: safe with MARGIN >= 2E)
        float thb[4][4];
        if (nt == t0) {
            // seed: butterfly tile-t0 row-min FIRST so t0 capture doesn't flood
            #pragma unroll
            for (int i = 0; i < 4; ++i)
                #pragma unroll
                for (int r = 0; r < 4; ++r) rowmin_reg[i][r] = r4[i][r];
            #pragma unroll
            for (int st = 1; st <= 8; st <<= 1)
                #pragma unroll
                for (int i = 0; i < 4; ++i)
                    #pragma unroll
                    for (int r = 0; r < 4; ++r)
                        rowmin_reg[i][r] = fminf(rowmin_reg[i][r], __shfl_xor(rowmin_reg[i][r], st, 64));
            #pragma unroll
            for (int i = 0; i < 4; ++i)
                #pragma unroll
                for (int r = 0; r < 4; ++r) thb[i][r] = rowmin_reg[i][r];
        } else {
            #pragma unroll
            for (int i = 0; i < 4; ++i)
                #pragma unroll
                for (int r = 0; r < 4; ++r) thb[i][r] = fminf(rowmin_reg[i][r], r4[i][r]);
        }

        bool anyhit = false;
        #pragma unroll
        for (int i = 0; i < 4; ++i)
            #pragma unroll
            for (int r = 0; r < 4; ++r)
                anyhit = anyhit || (r4[i][r] < thb[i][r] + MARGIN);

        if (__any(anyhit)) {
            u32 cnt = 0;
            #pragma unroll
            for (int i = 0; i < 4; ++i)
                #pragma unroll
                for (int r = 0; r < 4; ++r) {
                    float th = thb[i][r] + MARGIN;
                    if (r4[i][r] < th) {
                        #pragma unroll
                        for (int c = 0; c < 4; ++c)
                            cnt += (fmaf(-2.f, acc[i][c][r], t2v[c]) < th) ? 1u : 0u;
                    }
                }
            u32 pre = cnt;
            #pragma unroll
            for (int d = 1; d < 64; d <<= 1) {
                u32 v = __shfl_up(pre, d, 64);
                if (L >= d) pre += v;
            }
            u32 total = __shfl(pre, 63, 64);
            u32 woff = wcount + pre - cnt;
            #pragma unroll
            for (int i = 0; i < 4; ++i)
                #pragma unroll
                for (int r = 0; r < 4; ++r) {
                    float th = thb[i][r] + MARGIN;
                    if (r4[i][r] < th) {
                        const int q = mb * 256 + w * 64 + i * 16 + (L >> 4) * 4 + r;
                        #pragma unroll
                        for (int c = 0; c < 4; ++c) {
                            float s = fmaf(-2.f, acc[i][c][r], t2v[c]);
                            if (s < th) {
                                if (woff < WCAP)
                                    wreg[woff] = ((u64)__float_as_uint(s) << 32)
                                               | (u64)(((u32)q << 16) | (u32)(colb + c * 16));
                                woff++;
                            }
                        }
                    }
                }
            wcount += total;
        }

        // fold per-lane + full 16-lane butterfly EVERY tile -> tightest thresholds
        #pragma unroll
        for (int i = 0; i < 4; ++i)
            #pragma unroll
            for (int r = 0; r < 4; ++r)
                rowmin_reg[i][r] = fminf(rowmin_reg[i][r], r4[i][r]);
        #pragma unroll
        for (int st = 1; st <= 8; st <<= 1)
            #pragma unroll
            for (int i = 0; i < 4; ++i)
                #pragma unroll
                for (int r = 0; r < 4; ++r)
                    rowmin_reg[i][r] = fminf(rowmin_reg[i][r], __shfl_xor(rowmin_reg[i][r], st, 64));

        __syncthreads();   // drains next-tile stage + protects buffer reuse
    }

    // ---- final: exact chunk row-min + candidate count ----
    if ((L & 15) == 0) {
        #pragma unroll
        for (int i = 0; i < 4; ++i)
            #pragma unroll
            for (int r = 0; r < 4; ++r) {
                int q = mb * 256 + w * 64 + i * 16 + (L >> 4) * 4 + r;
                chunkmin[(size_t)q * nch + chunk] = rowmin_reg[i][r];
            }
    }
    if (L == 0) wavecnt[gwave] = (wcount < WCAP) ? wcount : WCAP;
    #undef TBASE_U32
}

// ---------------- global bf16 row-min: gmin[q] = min over chunks ----------------
__global__ void reduce_gmin(const float* __restrict__ chunkmin, float* __restrict__ gmin,
                            int B, int nch) {
    const int q = blockIdx.x * 4 + (threadIdx.x >> 6);
    const int c = threadIdx.x & 63;
    if (q >= B) return;
    float v = (c < nch) ? chunkmin[(size_t)q * nch + c] : 1e30f;
    #pragma unroll
    for (int st = 1; st < 64; st <<= 1) v = fminf(v, __shfl_xor(v, st, 64));
    if (c == 0) gmin[q] = v;
}

// ---------------- filtered exact fp32 rescore: ballot-compacted, wave-cooperative ----------------
__global__ void rescore(const float* __restrict__ x, const float* __restrict__ Xt,
                        const float* __restrict__ t2, const float* __restrict__ gmin,
                        const u32* __restrict__ wavecnt, const u64* __restrict__ cands,
                        u64* __restrict__ best) {
    const int L = threadIdx.x & 63;
    const int gw = blockIdx.x * (blockDim.x >> 6) + (threadIdx.x >> 6);
    if (gw >= NWAVE_CAP) return;
    u32 cnt = wavecnt[gw];
    if (cnt > WCAP) cnt = WCAP;
    const u64* reg = cands + (size_t)gw * WCAP;
    for (u32 base = 0; base < cnt; base += 64) {
        u32 i = base + L;
        u64 rec = 0; bool pass = false;
        if (i < cnt) {
            rec = reg[i];                                   // coalesced 512 B
            float sb = __uint_as_float((u32)(rec >> 32));
            int q = (int)((rec >> 16) & 0xFFFFu);
            pass = sb < gmin[q] + FMARGIN;
        }
        u64 bal = __ballot(pass);
        while (bal) {
            int j = __ffsll((unsigned long long)bal) - 1;
            bal &= bal - 1;
            u64 r2 = __shfl(rec, j, 64);
            int q = (int)((r2 >> 16) & 0xFFFFu);
            int n = (int)(r2 & 0xFFFFu);
            float4 a = *((const float4*)(x  + (size_t)q * F_DIM) + L);
            float4 b = *((const float4*)(Xt + (size_t)n * F_DIM) + L);
            float d = fmaf(a.x, b.x, fmaf(a.y, b.y, fmaf(a.z, b.z, a.w * b.w)));
            #pragma unroll
            for (int st = 32; st > 0; st >>= 1) d += __shfl_xor(d, st, 64);
            if (L == 0) {
                float s = fmaf(-2.f, d, t2[n]);
                u64 p = ((u64)ordf(s) << 32) | (u32)n;
                atomicMin(&best[q], p);
            }
        }
    }
}

// ---------------- gather Y[nearest] ----------------
__global__ void gather_kernel(const float* __restrict__ Y, const u64* __restrict__ best,
                              float* __restrict__ out, int B, int N) {
    int gid = blockIdx.x * blockDim.x + threadIdx.x;
    int total = B * O_DIM;
    if (gid >= total) return;
    int b = gid / O_DIM;
    int o = gid - b * O_DIM;
    u32 n = (u32)(best[b] & 0xFFFFFFFFull);
    if (n >= (u32)N) n = 0;   // defensive
    out[gid] = Y[(size_t)n * O_DIM + o];
}

// ================= fp32 fallback (proven Round-1 path, used if ws too small) =================
#define BM 128
#define BN 128
#define BK 16
#define NSPLIT 64
#define LDA (BM + 4)

__global__ __launch_bounds__(256) void knn_main_fp32(
    const float* __restrict__ Xq, const float* __restrict__ Xt,
    const float* __restrict__ t2, u64* __restrict__ best, int N)
{
    __shared__ float As[BK][LDA];
    __shared__ float Bs[BK][LDA];
    __shared__ u64 red[BM][17];

    const int tid = threadIdx.x;
    const int tx = tid & 15;
    const int ty = tid >> 4;
    const int m0 = blockIdx.y * BM;
    const int CHUNK = (N + NSPLIT - 1) / NSPLIT;
    const int n0c = blockIdx.x * CHUNK;
    const int n1c = min(N, n0c + CHUNK);

    u64 bestv[8];
    #pragma unroll
    for (int i = 0; i < 8; ++i) bestv[i] = ~0ull;

    const int srow = tid >> 2;
    const int scol4 = (tid & 3) * 4;

    for (int nt = n0c; nt < n1c; nt += BN) {
        float accl[8][8];
        #pragma unroll
        for (int i = 0; i < 8; ++i)
            #pragma unroll
            for (int j = 0; j < 8; ++j) accl[i][j] = 0.f;
        for (int k0 = 0; k0 < F_DIM; k0 += BK) {
            #pragma unroll
            for (int h = 0; h < 2; ++h) {
                int row = h * 64 + srow;
                float4 av = *(const float4*)(Xq + (size_t)(m0 + row) * F_DIM + k0 + scol4);
                As[scol4 + 0][row] = av.x; As[scol4 + 1][row] = av.y;
                As[scol4 + 2][row] = av.z; As[scol4 + 3][row] = av.w;
                int n = nt + row;
                float4 bv = make_float4(0.f, 0.f, 0.f, 0.f);
                if (n < n1c) bv = *(const float4*)(Xt + (size_t)n * F_DIM + k0 + scol4);
                Bs[scol4 + 0][row] = bv.x; Bs[scol4 + 1][row] = bv.y;
                Bs[scol4 + 2][row] = bv.z; Bs[scol4 + 3][row] = bv.w;
            }
            __syncthreads();
            #pragma unroll
            for (int k = 0; k < BK; ++k) {
                float4 a0 = *(const float4*)&As[k][ty * 4];
                float4 a1 = *(const float4*)&As[k][64 + ty * 4];
                float4 b0 = *(const float4*)&Bs[k][tx * 4];
                float4 b1 = *(const float4*)&Bs[k][64 + tx * 4];
                float am[8] = {a0.x, a0.y, a0.z, a0.w, a1.x, a1.y, a1.z, a1.w};
                float bn[8] = {b0.x, b0.y, b0.z, b0.w, b1.x, b1.y, b1.z, b1.w};
                #pragma unroll
                for (int i = 0; i < 8; ++i)
                    #pragma unroll
                    for (int j = 0; j < 8; ++j)
                        accl[i][j] = fmaf(am[i], bn[j], accl[i][j]);
            }
            __syncthreads();
        }
        #pragma unroll
        for (int j = 0; j < 8; ++j) {
            int nl = (j < 4) ? (tx * 4 + j) : (64 + tx * 4 + (j - 4));
            int n = nt + nl;
            if (n < n1c) {
                float t2v = t2[n];
                #pragma unroll
                for (int i = 0; i < 8; ++i) {
                    float score = fmaf(-2.f, accl[i][j], t2v);
                    u64 p = ((u64)ordf(score) << 32) | (u32)n;
                    bestv[i] = (p < bestv[i]) ? p : bestv[i];
                }
            }
        }
    }
    #pragma unroll
    for (int i = 0; i < 8; ++i) {
        int ml = (i < 4) ? (ty * 4 + i) : (64 + ty * 4 + (i - 4));
        red[ml][tx] = bestv[i];
    }
    __syncthreads();
    if (tid < BM) {
        u64 b = red[tid][0];
        #pragma unroll
        for (int t = 1; t < 16; ++t) { u64 v = red[tid][t]; b = (v < b) ? v : b; }
        atomicMin(&best[m0 + tid], b);
    }
}

// ================= launch =================
extern "C" void kernel_launch(void* const* d_in, const int* in_sizes, int n_in,
                              void* d_out, int out_size, void* d_ws, size_t ws_size,
                              hipStream_t stream) {
    const float* x  = (const float*)d_in[0];
    const float* Xt = (const float*)d_in[1];
    const float* Yt = (const float*)d_in[2];
    float* out = (float*)d_out;

    const int B = in_sizes[0] / F_DIM;        // 2048
    const int N = in_sizes[1] / F_DIM;        // 50000
    const int NT128 = (N + 127) / 128;        // 391
    const int Npad = NT128 * 128;             // 50048
    const int NT64 = NT128 * 2;               // 782
    const int MB = B / 256;                   // 8
    const int MT128 = B / 128;                // 16
    const int NCH = 64;                       // 8*64 = 512 blocks = 2/CU

    char* wsp = (char*)d_ws;
    size_t off = 0;
    auto nxt = [&](size_t bytes) {
        char* p = wsp + off;
        off = (off + bytes + 255) & ~(size_t)255;
        return p;
    };
    float* t2       = (float*)nxt((size_t)Npad * 4);
    u64*   best     = (u64*)  nxt((size_t)B * 8);
    u32*   wavecnt  = (u32*)  nxt((size_t)NWAVE_CAP * 4);
    float* gmin     = (float*)nxt((size_t)B * 4);
    float* chunkmin = (float*)nxt((size_t)B * NCH * 4);
    u64*   cands    = (u64*)  nxt((size_t)NWAVE_CAP * WCAP * 8);
    u16*   xbf      = (u16*)  nxt((size_t)B * F_DIM * 2);
    u16*   xtbf     = (u16*)  nxt((size_t)Npad * F_DIM * 2);
    size_t required = off;

    init_kernel<<<(B + 255) / 256, 256, 0, stream>>>(best, B);

    if (ws_size >= required && B % 256 == 0 && MB * NCH * 4 <= NWAVE_CAP) {
        convert_tile<<<dim3(MT128, 4), 256, 0, stream>>>(x, xbf, (float*)nullptr, B, 0);
        convert_tile<<<dim3(NT128, 4), 256, 0, stream>>>(Xt, xtbf, t2, N, 1);   // fused t2
        knn_mfma<<<dim3(MB, NCH), 256, 0, stream>>>(xbf, xtbf, t2, chunkmin, wavecnt, cands, NT64, NCH);
        reduce_gmin<<<(B + 3) / 4, 256, 0, stream>>>(chunkmin, gmin, B, NCH);
        rescore<<<NWAVE_CAP / 4, 256, 0, stream>>>(x, Xt, t2, gmin, wavecnt, cands, best);
    } else {
        t2_kernel<<<(N + 3) / 4, 256, 0, stream>>>(Xt, t2, N, N);
        dim3 grid(NSPLIT, B / BM);
        knn_main_fp32<<<grid, 256, 0, stream>>>(x, Xt, t2, best, N);
    }

    int total = B * O_DIM;
    gather_kernel<<<(total + 255) / 256, 256, 0, stream>>>(Yt, best, out, B, N);
}

// Round 14
// 281.705 us; speedup vs baseline: 1.2203x; 1.0522x over previous
//
#include <hip/hip_runtime.h>
#include <stdint.h>

typedef unsigned short u16;
typedef unsigned int   u32;
typedef unsigned long long u64;

#define F_DIM 256
#define O_DIM 24
#define MARGIN  3.0f      // capture margin (>= 2E bf16-vs-fp32 score bound; validated R2-R13)
#define FMARGIN 3.0f      // rescore global filter margin (same bound)
#define WCAP 1024         // candidate slots per capture-wave (8 B each)
#define NWAVE_CAP 2048    // 8 mb * 64 chunks * 4 waves

#define AS1 __attribute__((address_space(1)))
#define AS3 __attribute__((address_space(3)))

typedef __bf16 bf16x8 __attribute__((ext_vector_type(8)));
typedef float  f32x4  __attribute__((ext_vector_type(4)));

__device__ __forceinline__ u32 ordf(float s) {
    u32 b = __float_as_uint(s);
    return (b & 0x80000000u) ? ~b : (b | 0x80000000u);
}
__device__ __forceinline__ u16 f2bf(float f) {   // round-to-nearest-even
    u32 u = __float_as_uint(f);
    u32 r = (u + 0x7FFFu + ((u >> 16) & 1u)) >> 16;
    return (u16)r;
}

// ---------------- init ----------------
__global__ void init_kernel(u64* best, int B) {
    int i = blockIdx.x * blockDim.x + threadIdx.x;
    if (i < B) best[i] = ~0ull;
}

// ---------------- t2 (fallback path only) ----------------
__global__ void t2_kernel(const float* __restrict__ X, float* __restrict__ t2,
                          int N, int Npad) {
    int tid = threadIdx.x;
    int row = blockIdx.x * 4 + (tid >> 6);
    int lane = tid & 63;
    if (row >= Npad) return;
    if (row >= N) { if (lane == 0) t2[row] = 1e30f; return; }
    float4 v = ((const float4*)(X + (size_t)row * F_DIM))[lane];
    float s = v.x * v.x + v.y * v.y + v.z * v.z + v.w * v.w;
    #pragma unroll
    for (int off = 32; off > 0; off >>= 1) s += __shfl_down(s, off, 64);
    if (lane == 0) t2[row] = s;
}

// ---------------- coalesced converter: fp32 row-major -> bf16 fragment order ----------------
__global__ __launch_bounds__(256) void convert_tile(const float* __restrict__ src,
        u16* __restrict__ dst, float* __restrict__ t2out, int nrows, int do_t2) {
    __shared__ u16 tl[8192];   // 16 KB
    const int tid = threadIdx.x;
    const int t = blockIdx.x, p = blockIdx.y;
    const int w = tid >> 6, L = tid & 63;
    const int col = L * 4;
    const int ks = col >> 5, j = col & 7, lhi = ((col >> 3) & 3) << 4;
    #pragma unroll
    for (int i = 0; i < 8; ++i) {
        int rloc = i * 4 + w;
        int grow = t * 128 + p * 32 + rloc;
        float4 v = make_float4(0.f, 0.f, 0.f, 0.f);
        if (grow < nrows) v = *(const float4*)(src + (size_t)grow * F_DIM + col);
        if (do_t2) {
            float s = v.x * v.x + v.y * v.y + v.z * v.z + v.w * v.w;
            #pragma unroll
            for (int off = 32; off > 0; off >>= 1) s += __shfl_down(s, off, 64);
            if (L == 0) t2out[grow] = (grow < nrows) ? s : 1e30f;
        }
        u16* q = &tl[ks * 1024 + (rloc >> 4) * 512 + (((rloc & 15) | lhi)) * 8 + j];
        q[0] = f2bf(v.x); q[1] = f2bf(v.y); q[2] = f2bf(v.z); q[3] = f2bf(v.w);
    }
    __syncthreads();
    const uint4* s4 = (const uint4*)tl;
    uint4* d4 = (uint4*)(dst + (size_t)t * 32768);
    #pragma unroll
    for (int v = 0; v < 4; ++v) {
        int lin = v * 256 + tid;
        int ksc = lin >> 7, subl = (lin >> 6) & 1, lane = lin & 63;
        d4[(ksc * 8 + 2 * p + subl) * 64 + lane] = s4[lin];
    }
}

// ---------------- main: R5 geometry AND cadence (256 thr, M=256, butterfly/4) ----------------
// grid = dim3(MB=8, NCH=64): linear id = mb + 8*chunk -> all 64 blocks of one mb land
// on ONE XCD (A slice L2-resident); the 8 mb-partners of a chunk run on 8 XCDs in
// lockstep -> first B miss fills L3, 7 partners hit (R5 measured: 113 MB FETCH, 121 us).
__global__ __launch_bounds__(256, 2) void knn_mfma(
    const u16* __restrict__ xbf, const u16* __restrict__ xtbf,
    const float* __restrict__ t2, float* __restrict__ chunkmin,
    u32* __restrict__ wavecnt, u64* __restrict__ cands,
    int ntiles /*64-col tiles*/, int nch)
{
    __shared__ u16 sB[2][16384];   // 2 x 32 KB

    const int tid = threadIdx.x;
    const int L = tid & 63, w = tid >> 6;   // 4 waves
    const int mb = blockIdx.x;              // 256-row m-block (8)
    const int chunk = blockIdx.y;           // 64
    const int gwave = (mb * 64 + chunk) * 4 + w;
    const int t0 = (int)(((long long)chunk * ntiles) / nch);
    const int t1 = (int)(((long long)(chunk + 1) * ntiles) / nch);

    #define TBASE_U32(nt) ((const AS1 u32*)xtbf + (size_t)((nt) >> 1) * 16384 + (size_t)((nt) & 1) * 1024)

    // ---- stage first B tile (async, 8 x 256 threads x 16 B = 32 KB) ----
    {
        const AS1 u32* gp = TBASE_U32(t0);
        AS3 u32* lb = (AS3 u32*)&sB[0][0];
        #pragma unroll
        for (int ks = 0; ks < 8; ++ks)
            __builtin_amdgcn_global_load_lds(gp + (size_t)ks * 2048 + (size_t)tid * 4,
                                             lb + ks * 1024 + w * 256, 16, 0, 0);
    }

    // ---- A fragments in registers: wave w owns rows mb*256 + w*64 .. +63 ----
    bf16x8 areg[32];
    {
        const int t128 = mb * 2 + (w >> 1);
        const u16* base = xbf + (size_t)t128 * 32768 + (size_t)((w & 1) * 4) * 512 + (size_t)L * 8;
        #pragma unroll
        for (int ks = 0; ks < 8; ++ks)
            #pragma unroll
            for (int i = 0; i < 4; ++i)
                areg[ks * 4 + i] = *(const bf16x8*)(base + ks * 4096 + i * 512);
    }

    float rowmin_reg[4][4];
    #pragma unroll
    for (int i = 0; i < 4; ++i)
        #pragma unroll
        for (int r = 0; r < 4; ++r) rowmin_reg[i][r] = 1e30f;

    u32 wcount = 0;
    u64* const wreg = cands + (size_t)gwave * WCAP;

    __syncthreads();   // first B tile staged

    for (int nt = t0; nt < t1; ++nt) {
        const int cur = (nt - t0) & 1;
        if (nt + 1 < t1) {   // stage next tile into other buffer (drains at end barrier)
            const AS1 u32* gp = TBASE_U32(nt + 1);
            AS3 u32* lb = (AS3 u32*)&sB[cur ^ 1][0];
            #pragma unroll
            for (int ks = 0; ks < 8; ++ks)
                __builtin_amdgcn_global_load_lds(gp + (size_t)ks * 2048 + (size_t)tid * 4,
                                                 lb + ks * 1024 + w * 256, 16, 0, 0);
        }

        float t2v[4];
        #pragma unroll
        for (int c = 0; c < 4; ++c) t2v[c] = t2[nt * 64 + (L & 15) + c * 16];

        f32x4 acc[4][4];
        #pragma unroll
        for (int i = 0; i < 4; ++i)
            #pragma unroll
            for (int c = 0; c < 4; ++c)
                #pragma unroll
                for (int r = 0; r < 4; ++r) acc[i][c][r] = 0.f;

        #pragma unroll
        for (int ks = 0; ks < 8; ++ks) {
            bf16x8 bc[4];
            #pragma unroll
            for (int c = 0; c < 4; ++c)
                bc[c] = *(const bf16x8*)&sB[cur][ks * 2048 + c * 512 + L * 8];
            #pragma unroll
            for (int i = 0; i < 4; ++i)
                #pragma unroll
                for (int c = 0; c < 4; ++c)
                    acc[i][c] = __builtin_amdgcn_mfma_f32_16x16x32_bf16(areg[ks * 4 + i], bc[c], acc[i][c], 0, 0, 0);
        }

        // ---- epilogue ----
        const int colb = nt * 64 + (L & 15);
        float r4[4][4];
        #pragma unroll
        for (int i = 0; i < 4; ++i) {
            #pragma unroll
            for (int r = 0; r < 4; ++r) r4[i][r] = 1e30f;
            #pragma unroll
            for (int c = 0; c < 4; ++c)
                #pragma unroll
                for (int r = 0; r < 4; ++r)
                    r4[i][r] = fminf(r4[i][r], fmaf(-2.f, acc[i][c][r], t2v[c]));
        }

        // threshold base (subset-min of the row's bf16 scores: safe with MARGIN >= 2E)
        float thb[4][4];
        if (nt == t0) {
            // seed: butterfly tile-t0 row-min FIRST so t0 capture doesn't flood
            #pragma unroll
            for (int i = 0; i < 4; ++i)
                #pragma unroll
                for (int r = 0; r < 4; ++r) rowmin_reg[i][r] = r4[i][r];
            #pragma unroll
            for (int st = 1; st <= 8; st <<= 1)
                #pragma unroll
                for (int i = 0; i < 4; ++i)
                    #pragma unroll
                    for (int r = 0; r < 4; ++r)
                        rowmin_reg[i][r] = fminf(rowmin_reg[i][r], __shfl_xor(rowmin_reg[i][r], st, 64));
            #pragma unroll
            for (int i = 0; i < 4; ++i)
                #pragma unroll
                for (int r = 0; r < 4; ++r) thb[i][r] = rowmin_reg[i][r];
        } else {
            #pragma unroll
            for (int i = 0; i < 4; ++i)
                #pragma unroll
                for (int r = 0; r < 4; ++r) thb[i][r] = fminf(rowmin_reg[i][r], r4[i][r]);
        }

        bool anyhit = false;
        #pragma unroll
        for (int i = 0; i < 4; ++i)
            #pragma unroll
            for (int r = 0; r < 4; ++r)
                anyhit = anyhit || (r4[i][r] < thb[i][r] + MARGIN);

        if (__any(anyhit)) {
            u32 cnt = 0;
            #pragma unroll
            for (int i = 0; i < 4; ++i)
                #pragma unroll
                for (int r = 0; r < 4; ++r) {
                    float th = thb[i][r] + MARGIN;
                    if (r4[i][r] < th) {
                        #pragma unroll
                        for (int c = 0; c < 4; ++c)
                            cnt += (fmaf(-2.f, acc[i][c][r], t2v[c]) < th) ? 1u : 0u;
                    }
                }
            u32 pre = cnt;
            #pragma unroll
            for (int d = 1; d < 64; d <<= 1) {
                u32 v = __shfl_up(pre, d, 64);
                if (L >= d) pre += v;
            }
            u32 total = __shfl(pre, 63, 64);
            u32 woff = wcount + pre - cnt;
            #pragma unroll
            for (int i = 0; i < 4; ++i)
                #pragma unroll
                for (int r = 0; r < 4; ++r) {
                    float th = thb[i][r] + MARGIN;
                    if (r4[i][r] < th) {
                        const int q = mb * 256 + w * 64 + i * 16 + (L >> 4) * 4 + r;
                        #pragma unroll
                        for (int c = 0; c < 4; ++c) {
                            float s = fmaf(-2.f, acc[i][c][r], t2v[c]);
                            if (s < th) {
                                if (woff < WCAP)
                                    wreg[woff] = ((u64)__float_as_uint(s) << 32)
                                               | (u64)(((u32)q << 16) | (u32)(colb + c * 16));
                                woff++;
                            }
                        }
                    }
                }
            wcount += total;
        }

        // fold per-lane; full 16-lane butterfly only every 4th tile (R5 cadence —
        // measured best: R5 121us/113MB vs R13 every-tile 185us/305MB)
        #pragma unroll
        for (int i = 0; i < 4; ++i)
            #pragma unroll
            for (int r = 0; r < 4; ++r)
                rowmin_reg[i][r] = fminf(rowmin_reg[i][r], r4[i][r]);
        if (((nt - t0) & 3) == 3) {
            #pragma unroll
            for (int st = 1; st <= 8; st <<= 1)
                #pragma unroll
                for (int i = 0; i < 4; ++i)
                    #pragma unroll
                    for (int r = 0; r < 4; ++r)
                        rowmin_reg[i][r] = fminf(rowmin_reg[i][r], __shfl_xor(rowmin_reg[i][r], st, 64));
        }

        __syncthreads();   // drains next-tile stage + protects buffer reuse
    }

    // ---- final: exact chunk row-min + candidate count ----
    #pragma unroll
    for (int st = 1; st <= 8; st <<= 1)
        #pragma unroll
        for (int i = 0; i < 4; ++i)
            #pragma unroll
            for (int r = 0; r < 4; ++r)
                rowmin_reg[i][r] = fminf(rowmin_reg[i][r], __shfl_xor(rowmin_reg[i][r], st, 64));
    if ((L & 15) == 0) {
        #pragma unroll
        for (int i = 0; i < 4; ++i)
            #pragma unroll
            for (int r = 0; r < 4; ++r) {
                int q = mb * 256 + w * 64 + i * 16 + (L >> 4) * 4 + r;
                chunkmin[(size_t)q * nch + chunk] = rowmin_reg[i][r];
            }
    }
    if (L == 0) wavecnt[gwave] = (wcount < WCAP) ? wcount : WCAP;
    #undef TBASE_U32
}

// ---------------- global bf16 row-min: gmin[q] = min over chunks ----------------
__global__ void reduce_gmin(const float* __restrict__ chunkmin, float* __restrict__ gmin,
                            int B, int nch) {
    const int q = blockIdx.x * 4 + (threadIdx.x >> 6);
    const int c = threadIdx.x & 63;
    if (q >= B) return;
    float v = (c < nch) ? chunkmin[(size_t)q * nch + c] : 1e30f;
    #pragma unroll
    for (int st = 1; st < 64; st <<= 1) v = fminf(v, __shfl_xor(v, st, 64));
    if (c == 0) gmin[q] = v;
}

// ---------------- filtered exact fp32 rescore: ballot-compacted, wave-cooperative ----------------
__global__ void rescore(const float* __restrict__ x, const float* __restrict__ Xt,
                        const float* __restrict__ t2, const float* __restrict__ gmin,
                        const u32* __restrict__ wavecnt, const u64* __restrict__ cands,
                        u64* __restrict__ best) {
    const int L = threadIdx.x & 63;
    const int gw = blockIdx.x * (blockDim.x >> 6) + (threadIdx.x >> 6);
    if (gw >= NWAVE_CAP) return;
    u32 cnt = wavecnt[gw];
    if (cnt > WCAP) cnt = WCAP;
    const u64* reg = cands + (size_t)gw * WCAP;
    for (u32 base = 0; base < cnt; base += 64) {
        u32 i = base + L;
        u64 rec = 0; bool pass = false;
        if (i < cnt) {
            rec = reg[i];                                   // coalesced 512 B
            float sb = __uint_as_float((u32)(rec >> 32));
            int q = (int)((rec >> 16) & 0xFFFFu);
            pass = sb < gmin[q] + FMARGIN;
        }
        u64 bal = __ballot(pass);
        while (bal) {
            int j = __ffsll((unsigned long long)bal) - 1;
            bal &= bal - 1;
            u64 r2 = __shfl(rec, j, 64);
            int q = (int)((r2 >> 16) & 0xFFFFu);
            int n = (int)(r2 & 0xFFFFu);
            float4 a = *((const float4*)(x  + (size_t)q * F_DIM) + L);
            float4 b = *((const float4*)(Xt + (size_t)n * F_DIM) + L);
            float d = fmaf(a.x, b.x, fmaf(a.y, b.y, fmaf(a.z, b.z, a.w * b.w)));
            #pragma unroll
            for (int st = 32; st > 0; st >>= 1) d += __shfl_xor(d, st, 64);
            if (L == 0) {
                float s = fmaf(-2.f, d, t2[n]);
                u64 p = ((u64)ordf(s) << 32) | (u32)n;
                atomicMin(&best[q], p);
            }
        }
    }
}

// ---------------- gather Y[nearest] ----------------
__global__ void gather_kernel(const float* __restrict__ Y, const u64* __restrict__ best,
                              float* __restrict__ out, int B, int N) {
    int gid = blockIdx.x * blockDim.x + threadIdx.x;
    int total = B * O_DIM;
    if (gid >= total) return;
    int b = gid / O_DIM;
    int o = gid - b * O_DIM;
    u32 n = (u32)(best[b] & 0xFFFFFFFFull);
    if (n >= (u32)N) n = 0;   // defensive
    out[gid] = Y[(size_t)n * O_DIM + o];
}

// ================= fp32 fallback (proven Round-1 path, used if ws too small) =================
#define BM 128
#define BN 128
#define BK 16
#define NSPLIT 64
#define LDA (BM + 4)

__global__ __launch_bounds__(256) void knn_main_fp32(
    const float* __restrict__ Xq, const float* __restrict__ Xt,
    const float* __restrict__ t2, u64* __restrict__ best, int N)
{
    __shared__ float As[BK][LDA];
    __shared__ float Bs[BK][LDA];
    __shared__ u64 red[BM][17];

    const int tid = threadIdx.x;
    const int tx = tid & 15;
    const int ty = tid >> 4;
    const int m0 = blockIdx.y * BM;
    const int CHUNK = (N + NSPLIT - 1) / NSPLIT;
    const int n0c = blockIdx.x * CHUNK;
    const int n1c = min(N, n0c + CHUNK);

    u64 bestv[8];
    #pragma unroll
    for (int i = 0; i < 8; ++i) bestv[i] = ~0ull;

    const int srow = tid >> 2;
    const int scol4 = (tid & 3) * 4;

    for (int nt = n0c; nt < n1c; nt += BN) {
        float accl[8][8];
        #pragma unroll
        for (int i = 0; i < 8; ++i)
            #pragma unroll
            for (int j = 0; j < 8; ++j) accl[i][j] = 0.f;
        for (int k0 = 0; k0 < F_DIM; k0 += BK) {
            #pragma unroll
            for (int h = 0; h < 2; ++h) {
                int row = h * 64 + srow;
                float4 av = *(const float4*)(Xq + (size_t)(m0 + row) * F_DIM + k0 + scol4);
                As[scol4 + 0][row] = av.x; As[scol4 + 1][row] = av.y;
                As[scol4 + 2][row] = av.z; As[scol4 + 3][row] = av.w;
                int n = nt + row;
                float4 bv = make_float4(0.f, 0.f, 0.f, 0.f);
                if (n < n1c) bv = *(const float4*)(Xt + (size_t)n * F_DIM + k0 + scol4);
                Bs[scol4 + 0][row] = bv.x; Bs[scol4 + 1][row] = bv.y;
                Bs[scol4 + 2][row] = bv.z; Bs[scol4 + 3][row] = bv.w;
            }
            __syncthreads();
            #pragma unroll
            for (int k = 0; k < BK; ++k) {
                float4 a0 = *(const float4*)&As[k][ty * 4];
                float4 a1 = *(const float4*)&As[k][64 + ty * 4];
                float4 b0 = *(const float4*)&Bs[k][tx * 4];
                float4 b1 = *(const float4*)&Bs[k][64 + tx * 4];
                float am[8] = {a0.x, a0.y, a0.z, a0.w, a1.x, a1.y, a1.z, a1.w};
                float bn[8] = {b0.x, b0.y, b0.z, b0.w, b1.x, b1.y, b1.z, b1.w};
                #pragma unroll
                for (int i = 0; i < 8; ++i)
                    #pragma unroll
                    for (int j = 0; j < 8; ++j)
                        accl[i][j] = fmaf(am[i], bn[j], accl[i][j]);
            }
            __syncthreads();
        }
        #pragma unroll
        for (int j = 0; j < 8; ++j) {
            int nl = (j < 4) ? (tx * 4 + j) : (64 + tx * 4 + (j - 4));
            int n = nt + nl;
            if (n < n1c) {
                float t2v = t2[n];
                #pragma unroll
                for (int i = 0; i < 8; ++i) {
                    float score = fmaf(-2.f, accl[i][j], t2v);
                    u64 p = ((u64)ordf(score) << 32) | (u32)n;
                    bestv[i] = (p < bestv[i]) ? p : bestv[i];
                }
            }
        }
    }
    #pragma unroll
    for (int i = 0; i < 8; ++i) {
        int ml = (i < 4) ? (ty * 4 + i) : (64 + ty * 4 + (i - 4));
        red[ml][tx] = bestv[i];
    }
    __syncthreads();
    if (tid < BM) {
        u64 b = red[tid][0];
        #pragma unroll
        for (int t = 1; t < 16; ++t) { u64 v = red[tid][t]; b = (v < b) ? v : b; }
        atomicMin(&best[m0 + tid], b);
    }
}

// ================= launch =================
extern "C" void kernel_launch(void* const* d_in, const int* in_sizes, int n_in,
                              void* d_out, int out_size, void* d_ws, size_t ws_size,
                              hipStream_t stream) {
    const float* x  = (const float*)d_in[0];
    const float* Xt = (const float*)d_in[1];
    const float* Yt = (const float*)d_in[2];
    float* out = (float*)d_out;

    const int B = in_sizes[0] / F_DIM;        // 2048
    const int N = in_sizes[1] / F_DIM;        // 50000
    const int NT128 = (N + 127) / 128;        // 391
    const int Npad = NT128 * 128;             // 50048
    const int NT64 = NT128 * 2;               // 782
    const int MB = B / 256;                   // 8
    const int MT128 = B / 128;                // 16
    const int NCH = 64;                       // 8*64 = 512 blocks = 2/CU

    char* wsp = (char*)d_ws;
    size_t off = 0;
    auto nxt = [&](size_t bytes) {
        char* p = wsp + off;
        off = (off + bytes + 255) & ~(size_t)255;
        return p;
    };
    float* t2       = (float*)nxt((size_t)Npad * 4);
    u64*   best     = (u64*)  nxt((size_t)B * 8);
    u32*   wavecnt  = (u32*)  nxt((size_t)NWAVE_CAP * 4);
    float* gmin     = (float*)nxt((size_t)B * 4);
    float* chunkmin = (float*)nxt((size_t)B * NCH * 4);
    u64*   cands    = (u64*)  nxt((size_t)NWAVE_CAP * WCAP * 8);
    u16*   xbf      = (u16*)  nxt((size_t)B * F_DIM * 2);
    u16*   xtbf     = (u16*)  nxt((size_t)Npad * F_DIM * 2);
    size_t required = off;

    init_kernel<<<(B + 255) / 256, 256, 0, stream>>>(best, B);

    if (ws_size >= required && B % 256 == 0 && MB * NCH * 4 <= NWAVE_CAP) {
        convert_tile<<<dim3(MT128, 4), 256, 0, stream>>>(x, xbf, (float*)nullptr, B, 0);
        convert_tile<<<dim3(NT128, 4), 256, 0, stream>>>(Xt, xtbf, t2, N, 1);   // fused t2
        knn_mfma<<<dim3(MB, NCH), 256, 0, stream>>>(xbf, xtbf, t2, chunkmin, wavecnt, cands, NT64, NCH);
        reduce_gmin<<<(B + 3) / 4, 256, 0, stream>>>(chunkmin, gmin, B, NCH);
        rescore<<<NWAVE_CAP / 4, 256, 0, stream>>>(x, Xt, t2, gmin, wavecnt, cands, best);
    } else {
        t2_kernel<<<(N + 3) / 4, 256, 0, stream>>>(Xt, t2, N, N);
        dim3 grid(NSPLIT, B / BM);
        knn_main_fp32<<<grid, 256, 0, stream>>>(x, Xt, t2, best, N);
    }

    int total = B * O_DIM;
    gather_kernel<<<(total + 255) / 256, 256, 0, stream>>>(Yt, best, out, B, N);
}